// Round 1
// baseline (18.461 us; speedup 1.0000x reference)
//
#include <hip/hip_runtime.h>

#define NBLOCKS 2048
#define TPB 256

__global__ __launch_bounds__(TPB) void diou_partial_kernel(
    const float4* __restrict__ pred,
    const float4* __restrict__ targ,
    float* __restrict__ partial,
    int n)
{
    int tid = blockIdx.x * blockDim.x + threadIdx.x;
    int stride = gridDim.x * blockDim.x;
    float acc = 0.0f;
    for (int i = tid; i < n; i += stride) {
        float4 p = pred[i];   // [x0, y0, x1, y1]
        float4 t = targ[i];

        // intersection
        float ltx = fmaxf(p.x, t.x), lty = fmaxf(p.y, t.y);
        float rbx = fminf(p.z, t.z), rby = fminf(p.w, t.w);
        float wx = fmaxf(rbx - ltx, 0.0f);
        float wy = fmaxf(rby - lty, 0.0f);
        float inter = wx * wy;

        // areas / union / iou
        float ap = (p.z - p.x) * (p.w - p.y);
        float at = (t.z - t.x) * (t.w - t.y);
        float uni = ap + at - inter;
        float iou = inter / uni;

        // squared center distance
        float dx = (p.x + p.z) * 0.5f - (t.x + t.z) * 0.5f;
        float dy = (p.y + p.w) * 0.5f - (t.y + t.w) * 0.5f;
        float cdist = dx * dx + dy * dy;

        // squared enclosing-box diagonal
        float ex = fmaxf(p.z, t.z) - fminf(p.x, t.x);
        float ey = fmaxf(p.w, t.w) - fminf(p.y, t.y);
        float diag = ex * ex + ey * ey;

        float diou = iou - cdist / diag;
        acc += 1.0f - diou;
    }

    // wave-64 reduction
    #pragma unroll
    for (int off = 32; off > 0; off >>= 1)
        acc += __shfl_down(acc, off, 64);

    __shared__ float smem[TPB / 64];
    int lane = threadIdx.x & 63;
    int wid  = threadIdx.x >> 6;
    if (lane == 0) smem[wid] = acc;
    __syncthreads();
    if (threadIdx.x == 0) {
        float b = 0.0f;
        #pragma unroll
        for (int w = 0; w < TPB / 64; ++w) b += smem[w];
        partial[blockIdx.x] = b;
    }
}

__global__ __launch_bounds__(1024) void final_reduce_kernel(
    const float* __restrict__ partial,
    float* __restrict__ out,
    int nb,
    float inv_n)
{
    float acc = 0.0f;
    for (int i = threadIdx.x; i < nb; i += blockDim.x)
        acc += partial[i];

    #pragma unroll
    for (int off = 32; off > 0; off >>= 1)
        acc += __shfl_down(acc, off, 64);

    __shared__ float smem[1024 / 64];
    int lane = threadIdx.x & 63;
    int wid  = threadIdx.x >> 6;
    if (lane == 0) smem[wid] = acc;
    __syncthreads();
    if (threadIdx.x == 0) {
        float b = 0.0f;
        #pragma unroll
        for (int w = 0; w < 1024 / 64; ++w) b += smem[w];
        out[0] = b * inv_n;
    }
}

extern "C" void kernel_launch(void* const* d_in, const int* in_sizes, int n_in,
                              void* d_out, int out_size, void* d_ws, size_t ws_size,
                              hipStream_t stream)
{
    const float4* pred = (const float4*)d_in[0];
    const float4* targ = (const float4*)d_in[1];
    float* out = (float*)d_out;
    float* partial = (float*)d_ws;  // NBLOCKS floats = 8 KB scratch

    int n = in_sizes[0] / 4;  // number of boxes (2,000,000)

    diou_partial_kernel<<<NBLOCKS, TPB, 0, stream>>>(pred, targ, partial, n);
    final_reduce_kernel<<<1, 1024, 0, stream>>>(partial, out, NBLOCKS, 1.0f / (float)n);
}